// Round 18
// baseline (57.497 us; speedup 1.0000x reference)
//
#include <hip/hip_runtime.h>
#include <math.h>

// NUFFT forward via separable phase + bf16 MFMA. No workspace.
// ksp[c,k] = sum_x Ex[k,x] * ( sum_y img[c,x,y] * Ey[k,y] )
// R18 = R17 one-shot structure with KB=128 (grid 256 = 4 coil-pairs x 64
// k-groups, exactly 1 block/CU). Each wave covers 32 k's (kt=0,1): the same
// 8 ds_read_b128 per x-tile feed 32 MFMAs (4:1, was 2:1) and total L2 image
// traffic halves 128->64 MB (the only knob that has ever moved time in this
// family: R12->R14). One-shot slab staging, ONE barrier, in-register Ey
// recurrence, proven swizzle & epilogue.

#define K_TOTAL 8192
#define KB      128         // k's per block (4 quarters of 32, kt=2 x 16)
#define NX      128
#define NY      128

typedef short  bf16x8 __attribute__((ext_vector_type(8)));
typedef float  f32x4  __attribute__((ext_vector_type(4)));

__device__ inline unsigned short f32_to_bf16_rne(float f) {
    unsigned int u = __float_as_uint(f);
    u += 0x7FFFu + ((u >> 16) & 1u);
    return (unsigned short)(u >> 16);
}
__device__ inline unsigned pack2(float a, float b) {
    return (unsigned)f32_to_bf16_rne(a) | ((unsigned)f32_to_bf16_rne(b) << 16);
}

__global__ __launch_bounds__(512, 1) void nufft_mfma_kernel(
    const float* __restrict__ imgR,
    const float* __restrict__ imgI,
    const float* __restrict__ trj,
    float* __restrict__ out)
{
    // whole-image slab for 2 coils: [coil2][RI][128 rows * 256 B], swizzled
    __shared__ __align__(16) unsigned short slab[2][2][128 * 128];

    const int tid = threadIdx.x;
    const int bid = blockIdx.x;
    const int cg  = bid >> 6;          // coil pair: 0..3 -> coils 2cg,2cg+1
    const int kg0 = (bid & 63) * KB;   // base k of this block
    const int c0  = cg * 2;

    const int wave = tid >> 6;      // 0..7
    const int lane = tid & 63;
    const int l15  = lane & 15;
    const int lg   = lane >> 4;     // 0..3
    const int c2   = wave & 1;      // coil within pair
    const int kq   = wave >> 1;     // k-quarter (32 k's)
    const int c    = c0 + c2;       // output coil

    // ---- staging assignment: thread = (rowgrp 0..15, seg 0..31) ----
    const int rowgrp = tid >> 5;
    const int seg    = tid & 31;

    // ---- one-shot staging: 8 chunks, 2-deep disjoint-register pipeline ----
    {
        float4 L0[4], L1[4];
        const float* bR0 = imgR + (c0 * NX) * NY + seg * 4;
        const float* bI0 = imgI + (c0 * NX) * NY + seg * 4;
        const float* bR1 = imgR + ((c0 + 1) * NX) * NY + seg * 4;
        const float* bI1 = imgI + ((c0 + 1) * NX) * NY + seg * 4;

        {   // chunk 0
            const int row = rowgrp;
            L0[0] = *(const float4*)(bR0 + row * NY);
            L0[1] = *(const float4*)(bI0 + row * NY);
            L0[2] = *(const float4*)(bR1 + row * NY);
            L0[3] = *(const float4*)(bI1 + row * NY);
        }
#pragma unroll
        for (int i = 0; i < 8; ++i) {
            float4* cu = (i & 1) ? L1 : L0;
            float4* nx = (i & 1) ? L0 : L1;
            if (i < 7) {
                const int row = rowgrp + 16 * (i + 1);
                nx[0] = *(const float4*)(bR0 + row * NY);
                nx[1] = *(const float4*)(bI0 + row * NY);
                nx[2] = *(const float4*)(bR1 + row * NY);
                nx[3] = *(const float4*)(bI1 + row * NY);
            }
            const int row = rowgrp + 16 * i;
            const int off = row * 256 + ((seg * 8) ^ ((row & 15) << 4));
            uint2 v;
            v.x = pack2(cu[0].x, cu[0].y); v.y = pack2(cu[0].z, cu[0].w);
            *(uint2*)((char*)&slab[0][0][0] + off) = v;
            v.x = pack2(cu[1].x, cu[1].y); v.y = pack2(cu[1].z, cu[1].w);
            *(uint2*)((char*)&slab[0][1][0] + off) = v;
            v.x = pack2(cu[2].x, cu[2].y); v.y = pack2(cu[2].z, cu[2].w);
            *(uint2*)((char*)&slab[1][0][0] + off) = v;
            v.x = pack2(cu[3].x, cu[3].y); v.y = pack2(cu[3].z, cu[3].w);
            *(uint2*)((char*)&slab[1][1][0] + off) = v;
        }
    }

    // ---- Ey A-fragments in registers via phase recurrence (overlaps loads) ----
    // A layout (16x16x32): row = lane&15 -> k = kq*32 + kt*16 + l15;
    // k slot y = ys*32 + lg*8 + m. Walk m by cmul with exp(-2πi ky/128).
    bf16x8 aR[2][4], aI[2][4];
#pragma unroll
    for (int kt = 0; kt < 2; ++kt) {
        const float ky = trj[(kg0 + kq * 32 + kt * 16 + l15) * 2 + 1];
        float u = -ky * (1.0f / 128.0f); u -= floorf(u);
        float s1i, s1r; __sincosf(6.283185307179586f * u, &s1i, &s1r);
#pragma unroll
        for (int ys = 0; ys < 4; ++ys) {
            const int y0 = ys * 32 + lg * 8;
            float t = -ky * (float)(y0 - 64) * (1.0f / 128.0f); t -= floorf(t);
            float ci_, cr_; __sincosf(6.283185307179586f * t, &ci_, &cr_);
#pragma unroll
            for (int m = 0; m < 8; ++m) {
                aR[kt][ys][m] = (short)f32_to_bf16_rne(cr_);
                aI[kt][ys][m] = (short)f32_to_bf16_rne(ci_);
                const float nr = cr_ * s1r - ci_ * s1i;
                ci_ = cr_ * s1i + ci_ * s1r;
                cr_ = nr;
            }
        }
    }

    // kx preload for stage C: k = kg0 + kq*32 + kt*16 + lg*4 + j
    float kxv[2][4];
#pragma unroll
    for (int kt = 0; kt < 2; ++kt)
#pragma unroll
        for (int j = 0; j < 4; ++j)
            kxv[kt][j] = trj[(kg0 + kq * 32 + kt * 16 + lg * 4 + j) * 2 + 0];

    __syncthreads();   // the ONLY barrier: slab fully staged & visible

    // ---- barrier-free compute: 8 x-tiles; 8 ds_reads feed 32 MFMAs each ----
    const char* sbR = (const char*)&slab[c2][0][0];
    const char* sbI = (const char*)&slab[c2][1][0];

    f32x4 outRe[2] = {{0,0,0,0},{0,0,0,0}};
    f32x4 outIm[2] = {{0,0,0,0},{0,0,0,0}};

#pragma unroll
    for (int nt = 0; nt < 8; ++nt) {
        const int x    = nt * 16 + l15;
        const int rowb = x * 256;

        f32x4 P[2] = {{0,0,0,0},{0,0,0,0}};
        f32x4 Q[2] = {{0,0,0,0},{0,0,0,0}};
        f32x4 U[2] = {{0,0,0,0},{0,0,0,0}};
        f32x4 V[2] = {{0,0,0,0},{0,0,0,0}};
#pragma unroll
        for (int ys = 0; ys < 4; ++ys) {
            const int inb = (lg * 16 + ys * 64) ^ (l15 << 4);
            const bf16x8 bR = *(const bf16x8*)(sbR + rowb + inb);
            const bf16x8 bI = *(const bf16x8*)(sbI + rowb + inb);
#pragma unroll
            for (int kt = 0; kt < 2; ++kt) {
                P[kt] = __builtin_amdgcn_mfma_f32_16x16x32_bf16(aR[kt][ys], bR, P[kt], 0, 0, 0);
                Q[kt] = __builtin_amdgcn_mfma_f32_16x16x32_bf16(aI[kt][ys], bI, Q[kt], 0, 0, 0);
                U[kt] = __builtin_amdgcn_mfma_f32_16x16x32_bf16(aR[kt][ys], bI, U[kt], 0, 0, 0);
                V[kt] = __builtin_amdgcn_mfma_f32_16x16x32_bf16(aI[kt][ys], bR, V[kt], 0, 0, 0);
            }
        }

        const float rx = (float)(x - 64) * (1.0f / 128.0f);
#pragma unroll
        for (int kt = 0; kt < 2; ++kt) {
#pragma unroll
            for (int j = 0; j < 4; ++j) {
                float t = -kxv[kt][j] * rx; t -= floorf(t);
                float eI_, eR_; __sincosf(6.283185307179586f * t, &eI_, &eR_);
                const float TR = P[kt][j] - Q[kt][j];
                const float TI = U[kt][j] + V[kt][j];
                outRe[kt][j] += eR_ * TR - eI_ * TI;
                outIm[kt][j] += eR_ * TI + eI_ * TR;
            }
        }
    }

    // ---- reduce over the 16 x-lanes; lanes with l15==0 write ----
#pragma unroll
    for (int kt = 0; kt < 2; ++kt) {
#pragma unroll
        for (int j = 0; j < 4; ++j) {
            float r_ = outRe[kt][j];
            float i_ = outIm[kt][j];
#pragma unroll
            for (int m = 1; m < 16; m <<= 1) {
                r_ += __shfl_xor(r_, m, 64);
                i_ += __shfl_xor(i_, m, 64);
            }
            if (l15 == 0) {
                const int kg = kg0 + kq * 32 + kt * 16 + lg * 4 + j;
                ((float2*)out)[c * K_TOTAL + kg] = make_float2(r_, i_);
            }
        }
    }
}

extern "C" void kernel_launch(void* const* d_in, const int* in_sizes, int n_in,
                              void* d_out, int out_size, void* d_ws, size_t ws_size,
                              hipStream_t stream) {
    const float* imgR = (const float*)d_in[0];
    const float* imgI = (const float*)d_in[1];
    const float* trj  = (const float*)d_in[2];
    float* out = (float*)d_out;

    hipLaunchKernelGGL(nufft_mfma_kernel, dim3(256), dim3(512), 0, stream,
                       imgR, imgI, trj, out);
}

// Round 19
// 20.849 us; speedup vs baseline: 2.7578x; 2.7578x over previous
//
#include <hip/hip_runtime.h>
#include <math.h>

// NUFFT forward via separable phase + bf16 MFMA. No workspace.
// ksp[c,k] = sum_x Ex[k,x] * ( sum_y img[c,x,y] * Ey[k,y] )
// R19: R17 per-wave structure (proven no-spill: aR[4]/aI[4], 4 accs,
// kxv[4]) scaled to KB=128 per BLOCK via more waves, not more per-wave
// registers (R18 lesson: 2x k/wave -> 180 VGPR -> spills at 3 TB/s HBM).
// Block = 1 coil x 128 k (8 waves = 8 k-octs) sharing a 64 KB single-coil
// slab; grid 512 = 8 coils x 64 k-groups; 2 resident blocks/CU (staging of
// one overlaps compute of the other). Total image L2 reads 128->64 MB,
// per-CU 512->256 KB. One barrier; barrier-free compute; proven swizzle.

#define K_TOTAL 8192
#define KB      128         // k's per block (8 octs of 16)
#define NX      128
#define NY      128

typedef short  bf16x8 __attribute__((ext_vector_type(8)));
typedef float  f32x4  __attribute__((ext_vector_type(4)));

__device__ inline unsigned short f32_to_bf16_rne(float f) {
    unsigned int u = __float_as_uint(f);
    u += 0x7FFFu + ((u >> 16) & 1u);
    return (unsigned short)(u >> 16);
}
__device__ inline unsigned pack2(float a, float b) {
    return (unsigned)f32_to_bf16_rne(a) | ((unsigned)f32_to_bf16_rne(b) << 16);
}

__global__ __launch_bounds__(512, 2) void nufft_mfma_kernel(
    const float* __restrict__ imgR,
    const float* __restrict__ imgI,
    const float* __restrict__ trj,
    float* __restrict__ out)
{
    // one-coil slab: [RI][128 rows * 256 B], swizzled in-row. 64 KB.
    __shared__ __align__(16) unsigned short slab[2][128 * 128];

    const int tid = threadIdx.x;
    const int bid = blockIdx.x;
    const int c   = bid >> 6;          // coil 0..7
    const int kg0 = (bid & 63) * KB;   // base k of this block

    const int wave = tid >> 6;      // 0..7 == k-oct
    const int lane = tid & 63;
    const int l15  = lane & 15;
    const int lg   = lane >> 4;     // 0..3

    // ---- staging assignment: thread = (rowgrp 0..15, seg 0..31) ----
    const int rowgrp = tid >> 5;
    const int seg    = tid & 31;

    // ---- one-shot staging: 8 chunks, 2-deep disjoint-register pipeline ----
    {
        float4 R0, I0, R1, I1;
        const float* bR = imgR + (c * NX) * NY + seg * 4;
        const float* bI = imgI + (c * NX) * NY + seg * 4;

        R0 = *(const float4*)(bR + rowgrp * NY);
        I0 = *(const float4*)(bI + rowgrp * NY);
#pragma unroll
        for (int i = 0; i < 8; ++i) {
            const bool even = (i & 1) == 0;
            if (i < 7) {
                const int rown = rowgrp + 16 * (i + 1);
                if (even) { R1 = *(const float4*)(bR + rown * NY);
                            I1 = *(const float4*)(bI + rown * NY); }
                else      { R0 = *(const float4*)(bR + rown * NY);
                            I0 = *(const float4*)(bI + rown * NY); }
            }
            const float4 vR = even ? R0 : R1;
            const float4 vI = even ? I0 : I1;
            const int row = rowgrp + 16 * i;
            const int off = row * 256 + ((seg * 8) ^ ((row & 15) << 4));
            uint2 v;
            v.x = pack2(vR.x, vR.y); v.y = pack2(vR.z, vR.w);
            *(uint2*)((char*)&slab[0][0] + off) = v;
            v.x = pack2(vI.x, vI.y); v.y = pack2(vI.z, vI.w);
            *(uint2*)((char*)&slab[1][0] + off) = v;
        }
    }

    // ---- Ey A-fragments in registers via phase recurrence (overlaps loads) ----
    // A layout (16x16x32): row = lane&15 -> k = kg0 + wave*16 + l15;
    // k slot y = ys*32 + lg*8 + m. Walk m by cmul with exp(-2πi ky/128).
    bf16x8 aR[4], aI[4];
    {
        const float ky = trj[(kg0 + wave * 16 + l15) * 2 + 1];
        float u = -ky * (1.0f / 128.0f); u -= floorf(u);
        float s1i, s1r; __sincosf(6.283185307179586f * u, &s1i, &s1r);
#pragma unroll
        for (int ys = 0; ys < 4; ++ys) {
            const int y0 = ys * 32 + lg * 8;
            float t = -ky * (float)(y0 - 64) * (1.0f / 128.0f); t -= floorf(t);
            float ci_, cr_; __sincosf(6.283185307179586f * t, &ci_, &cr_);
#pragma unroll
            for (int m = 0; m < 8; ++m) {
                aR[ys][m] = (short)f32_to_bf16_rne(cr_);
                aI[ys][m] = (short)f32_to_bf16_rne(ci_);
                const float nr = cr_ * s1r - ci_ * s1i;
                ci_ = cr_ * s1i + ci_ * s1r;
                cr_ = nr;
            }
        }
    }

    // kx preload for stage C: k = kg0 + wave*16 + lg*4 + j
    float kxv[4];
#pragma unroll
    for (int j = 0; j < 4; ++j)
        kxv[j] = trj[(kg0 + wave * 16 + lg * 4 + j) * 2 + 0];

    __syncthreads();   // the ONLY barrier: slab fully staged & visible

    // ---- barrier-free compute: 8 x-tiles of pure ds_read + MFMA + cmul ----
    const char* sbR = (const char*)&slab[0][0];
    const char* sbI = (const char*)&slab[1][0];

    f32x4 outRe = {0,0,0,0};
    f32x4 outIm = {0,0,0,0};

#pragma unroll
    for (int nt = 0; nt < 8; ++nt) {
        const int x    = nt * 16 + l15;
        const int rowb = x * 256;

        f32x4 P = {0,0,0,0}, Q = {0,0,0,0}, U = {0,0,0,0}, V = {0,0,0,0};
#pragma unroll
        for (int ys = 0; ys < 4; ++ys) {
            const int inb = (lg * 16 + ys * 64) ^ (l15 << 4);
            const bf16x8 bR = *(const bf16x8*)(sbR + rowb + inb);
            const bf16x8 bI = *(const bf16x8*)(sbI + rowb + inb);
            P = __builtin_amdgcn_mfma_f32_16x16x32_bf16(aR[ys], bR, P, 0, 0, 0);
            Q = __builtin_amdgcn_mfma_f32_16x16x32_bf16(aI[ys], bI, Q, 0, 0, 0);
            U = __builtin_amdgcn_mfma_f32_16x16x32_bf16(aR[ys], bI, U, 0, 0, 0);
            V = __builtin_amdgcn_mfma_f32_16x16x32_bf16(aI[ys], bR, V, 0, 0, 0);
        }

        const float rx = (float)(x - 64) * (1.0f / 128.0f);
#pragma unroll
        for (int j = 0; j < 4; ++j) {
            float t = -kxv[j] * rx; t -= floorf(t);
            float eI_, eR_; __sincosf(6.283185307179586f * t, &eI_, &eR_);
            const float TR = P[j] - Q[j];
            const float TI = U[j] + V[j];
            outRe[j] += eR_ * TR - eI_ * TI;
            outIm[j] += eR_ * TI + eI_ * TR;
        }
    }

    // ---- reduce over the 16 x-lanes; lanes with l15==0 write ----
#pragma unroll
    for (int j = 0; j < 4; ++j) {
        float r_ = outRe[j];
        float i_ = outIm[j];
#pragma unroll
        for (int m = 1; m < 16; m <<= 1) {
            r_ += __shfl_xor(r_, m, 64);
            i_ += __shfl_xor(i_, m, 64);
        }
        if (l15 == 0) {
            const int kg = kg0 + wave * 16 + lg * 4 + j;
            ((float2*)out)[c * K_TOTAL + kg] = make_float2(r_, i_);
        }
    }
}

extern "C" void kernel_launch(void* const* d_in, const int* in_sizes, int n_in,
                              void* d_out, int out_size, void* d_ws, size_t ws_size,
                              hipStream_t stream) {
    const float* imgR = (const float*)d_in[0];
    const float* imgI = (const float*)d_in[1];
    const float* trj  = (const float*)d_in[2];
    float* out = (float*)d_out;

    hipLaunchKernelGGL(nufft_mfma_kernel, dim3(512), dim3(512), 0, stream,
                       imgR, imgI, trj, out);
}